// Round 1
// baseline (385.168 us; speedup 1.0000x reference)
//
#include <hip/hip_runtime.h>

// Kalman filter, reformulated:
//   out[b][p] = alpha_p + sum_t Z[p][t] * x[b][t]
// where Z[p][t] = u_p . w_t, alpha_p = u_p . vstar + e_p.
// Shared precompute (kernel A):
//   block 0: P-recursion (transposed state PT = P^T in LDS) producing k_t,
//            with folded propagation V <- M_t V (V holds vstar and w-columns).
//   block 1: prediction-phase row chains u_p = h_q F_q ... F_32 and e_p.
// Kernel B: tiny GEMM using Z built from U and W (= final V).

constexpr int Hn  = 64;
constexpr int LBn = 32;
constexpr int PWn = 16;
constexpr int NC  = 33;   // V columns: col0 = bias (vstar), col 1+t = w_t
constexpr int SP  = 65;   // LDS stride for PT, Tm (all b32 access, 2-way free)
constexpr int SF  = 68;   // LDS stride for FTs (16B aligned for float4 bcast)
constexpr int SV  = 34;   // LDS stride for V

// ws layout (floats)
constexpr int WOFF_W = 0;        // 64*33
constexpr int WOFF_U = 64 * NC;  // 16*64
constexpr int WOFF_E = WOFF_U + PWn * Hn;  // 16

#define FMA16(acc, a, Bp)                                                     \
  {                                                                           \
    const float4 b0_ = (Bp)[0], b1_ = (Bp)[1], b2_ = (Bp)[2], b3_ = (Bp)[3];  \
    acc[0] += (a) * b0_.x;  acc[1] += (a) * b0_.y;                            \
    acc[2] += (a) * b0_.z;  acc[3] += (a) * b0_.w;                            \
    acc[4] += (a) * b1_.x;  acc[5] += (a) * b1_.y;                            \
    acc[6] += (a) * b1_.z;  acc[7] += (a) * b1_.w;                            \
    acc[8] += (a) * b2_.x;  acc[9] += (a) * b2_.y;                            \
    acc[10] += (a) * b2_.z; acc[11] += (a) * b2_.w;                           \
    acc[12] += (a) * b3_.x; acc[13] += (a) * b3_.y;                           \
    acc[14] += (a) * b3_.z; acc[15] += (a) * b3_.w;                           \
  }

__global__ __launch_bounds__(256) void kalmanA(
    const float* __restrict__ Fw, const float* __restrict__ Fb,
    const float* __restrict__ Hw, const float* __restrict__ Hb,
    const float* __restrict__ s0, const float* __restrict__ P0,
    const float* __restrict__ Q,  const float* __restrict__ R,
    float* __restrict__ ws) {
  const int tid  = threadIdx.x;
  const int lane = tid & 63;
  const int w    = tid >> 6;

  if (blockIdx.x == 1) {
    // ---- prediction-phase chains: u_p (row vectors), e_p (scalars) ----
    // u_p = h_{32+p} F_{32+p} F_{32+p-1} ... F_32
    // e_p = sum_s r^(s) . Fb_{q-s} + Hb_q   (r^(s) = chain intermediates)
    for (int pi = 0; pi < 4; ++pi) {
      const int p = w + pi * 4;
      const int q = LBn + p;
      float r = Hw[q * Hn + lane];
      float eacc = 0.f;
      for (int s = 0; s <= p; ++s) {
        const int m = q - s;
        eacc += r * Fb[m * Hn + lane];
        const float* Fm = Fw + m * Hn * Hn;
        float rn = 0.f;
        for (int j = 0; j < Hn; ++j) {
          rn += __shfl(r, j, 64) * Fm[j * Hn + lane];  // coalesced rows
        }
        r = rn;
      }
      #pragma unroll
      for (int o = 32; o >= 1; o >>= 1) eacc += __shfl_xor(eacc, o, 64);
      ws[WOFF_U + p * Hn + lane] = r;
      if (lane == 0) ws[WOFF_E + p] = eacc + Hb[q];
    }
    return;
  }

  // ---------------- block 0: shared P-recursion ----------------
  __shared__ float PT[Hn * SP];   // PT[l][i] = P[i][l] (transposed state)
  __shared__ float Tm[Hn * SP];   // Tm[j][l] = (P F^T)[j][l]
  __shared__ float FTs[Hn * SF];  // FTs[k][l] = F[l][k] (transposed F_t)
  __shared__ float V[Hn * SV];    // V[i][c]
  __shared__ float hv[Hn], kvs[Hn], hfv[Hn], dvs[Hn], Fbv[Hn], hPl[Hn];
  __shared__ float qv[NC];
  __shared__ float red1[4 * Hn], red2[4 * Hn], red3[4 * Hn];

  const float R0 = R[0];

  for (int idx = tid; idx < Hn * Hn; idx += 256) {
    const int i = idx >> 6, l = idx & 63;
    PT[l * SP + i] = P0[idx];
  }
  for (int idx = tid; idx < Hn * SV; idx += 256) {
    const int i = idx / SV, c = idx % SV;
    V[idx] = (c == 0 && i < Hn) ? s0[i] : 0.f;
  }
  __syncthreads();

  for (int t = 0; t < LBn; ++t) {
    // ---- stage FTs (transpose of F_t), hv, Fbv ----
    {
      const float* Ft = Fw + t * Hn * Hn;
      const int l = tid >> 2, k0 = (tid & 3) * 16;
      const float4* src = (const float4*)(Ft + l * Hn + k0);
      const float4 a0 = src[0], a1 = src[1], a2 = src[2], a3 = src[3];
      FTs[(k0 + 0) * SF + l] = a0.x;  FTs[(k0 + 1) * SF + l] = a0.y;
      FTs[(k0 + 2) * SF + l] = a0.z;  FTs[(k0 + 3) * SF + l] = a0.w;
      FTs[(k0 + 4) * SF + l] = a1.x;  FTs[(k0 + 5) * SF + l] = a1.y;
      FTs[(k0 + 6) * SF + l] = a1.z;  FTs[(k0 + 7) * SF + l] = a1.w;
      FTs[(k0 + 8) * SF + l] = a2.x;  FTs[(k0 + 9) * SF + l] = a2.y;
      FTs[(k0 + 10) * SF + l] = a2.z; FTs[(k0 + 11) * SF + l] = a2.w;
      FTs[(k0 + 12) * SF + l] = a3.x; FTs[(k0 + 13) * SF + l] = a3.y;
      FTs[(k0 + 14) * SF + l] = a3.z; FTs[(k0 + 15) * SF + l] = a3.w;
      if (tid < Hn) { hv[tid] = Hw[t * Hn + tid]; Fbv[tid] = Fb[t * Hn + tid]; }
    }
    __syncthreads();

    // ---- mm1: Tm[j][l] = sum_k P[j][k] F[l][k] = sum_k PT[k][j] FTs[k][l] ----
    {
      const int l0 = w * 16;
      float acc[16];
      #pragma unroll
      for (int c = 0; c < 16; ++c) acc[c] = 0.f;
      #pragma unroll 4
      for (int k = 0; k < Hn; ++k) {
        const float a = PT[k * SP + lane];               // coalesced, 2-way
        const float4* Bp = (const float4*)&FTs[k * SF + l0];  // bcast
        FMA16(acc, a, Bp)
      }
      #pragma unroll
      for (int c = 0; c < 16; ++c) Tm[lane * SP + l0 + c] = acc[c];
    }
    __syncthreads();

    // ---- mm2: P_pred[i][l] = sum_j F[i][j] Tm[j][l] + Q[i][l]; store PT ----
    {
      const int i0 = w * 16;
      float acc[16];
      #pragma unroll
      for (int c = 0; c < 16; ++c) acc[c] = 0.f;
      #pragma unroll 4
      for (int j = 0; j < Hn; ++j) {
        const float a = Tm[j * SP + lane];               // lane = l
        const float4* Bp = (const float4*)&FTs[j * SF + i0];  // F[i0..][j]
        FMA16(acc, a, Bp)
      }
      #pragma unroll
      for (int c = 0; c < 16; ++c)
        PT[lane * SP + i0 + c] = acc[c] + Q[(i0 + c) * Hn + lane];
    }
    __syncthreads();

    // ---- phase A: partial reductions (num, hP, hF) ----
    {
      float p1 = 0.f, p2 = 0.f, p3 = 0.f;
      const int jb = w * 16;
      for (int u = 0; u < 16; ++u) {
        const int j = jb + u;
        const float hj = hv[j];
        p1 += PT[j * SP + lane] * hj;    // num[i] partial (lane = i)
        p2 += PT[lane * SP + j] * hj;    // hP[l] partial  (lane = l)
        p3 += FTs[lane * SF + j] * hj;   // hF[j] partial  (lane = j)
      }
      red1[w * Hn + lane] = p1;
      red2[w * Hn + lane] = p2;
      red3[w * Hn + lane] = p3;
    }
    __syncthreads();

    // ---- phase B: wave 0 finalizes k, d, hF, hP ----
    if (w == 0) {
      const float num = red1[lane] + red1[Hn + lane] + red1[2 * Hn + lane] + red1[3 * Hn + lane];
      const float hP  = red2[lane] + red2[Hn + lane] + red2[2 * Hn + lane] + red2[3 * Hn + lane];
      const float hf  = red3[lane] + red3[Hn + lane] + red3[2 * Hn + lane] + red3[3 * Hn + lane];
      hfv[lane] = hf;
      hPl[lane] = hP;
      float sv = hv[lane] * num;
      #pragma unroll
      for (int o = 32; o >= 1; o >>= 1) sv += __shfl_xor(sv, o, 64);
      const float kvi = num / (sv + R0);
      kvs[lane] = kvi;
      const float fbl = Fbv[lane];
      float hb = hv[lane] * fbl;
      #pragma unroll
      for (int o = 32; o >= 1; o >>= 1) hb += __shfl_xor(hb, o, 64);
      dvs[lane] = fbl - kvi * (hb + Hb[t]);
    }
    __syncthreads();

    // ---- phase B2: q[c] (wave 0) + rank-1 P update (waves 1-3) ----
    if (w == 0) {
      if (lane < NC) {
        float acc = 0.f;
        for (int j = 0; j < Hn; ++j) acc += hfv[j] * V[j * SV + lane];
        qv[lane] = acc;
      }
    } else {
      for (int idx = tid - 64; idx < Hn * Hn; idx += 192) {
        const int i = idx & 63, l = idx >> 6;
        PT[l * SP + i] -= hPl[l] * kvs[i];
      }
    }
    __syncthreads();

    // ---- phase C: V propagation accumulate (Vnew = F V, rank-1 later) ----
    const int c0 = (w == 0) ? 0 : (9 + (w - 1) * 8);
    const int cn = (w == 0) ? 9 : 8;
    float vacc[9];
    #pragma unroll
    for (int ci = 0; ci < 9; ++ci) vacc[ci] = 0.f;
    for (int j = 0; j < Hn; ++j) {
      const float a = FTs[j * SF + lane];  // F[i][j], lane = i
      #pragma unroll
      for (int ci = 0; ci < 9; ++ci) vacc[ci] += a * V[j * SV + c0 + ci];
    }
    __syncthreads();

    // ---- phase D: finalize V writes ----
    #pragma unroll
    for (int ci = 0; ci < 9; ++ci) {
      if (ci < cn) {
        const int c = c0 + ci;
        float val = vacc[ci] - kvs[lane] * qv[c];
        if (c == 0) val += dvs[lane];
        if (c == t + 1) val = kvs[lane];
        V[lane * SV + c] = val;
      }
    }
    __syncthreads();
  }

  // write W = final V
  for (int idx = tid; idx < Hn * NC; idx += 256) {
    const int i = idx / NC, c = idx % NC;
    ws[WOFF_W + idx] = V[i * SV + c];
  }
}

__global__ __launch_bounds__(256) void kalmanB(
    const float* __restrict__ x, const float* __restrict__ ws,
    float* __restrict__ out) {
  __shared__ float Zl[PWn][NC + 1];
  __shared__ float xs[256 * NC];
  const int tid = threadIdx.x;
  const int b0  = blockIdx.x * 256;

  // build Z (redundant per block; tiny)
  for (int idx = tid; idx < PWn * NC; idx += 256) {
    const int p = idx / NC, c = idx % NC;
    const float* Up = ws + WOFF_U + p * Hn;
    float acc = 0.f;
    for (int i = 0; i < Hn; ++i) acc += Up[i] * ws[WOFF_W + i * NC + c];
    if (c == 0) acc += ws[WOFF_E + p];
    Zl[p][c] = acc;
  }
  // stage x tile (256 batches x 32)
  const float4* xv = (const float4*)(x + (size_t)b0 * LBn);
  #pragma unroll
  for (int r = 0; r < 8; ++r) {
    const int fi = tid + 256 * r;
    const float4 v = xv[fi];
    const int b  = fi >> 3;
    const int t0 = (fi & 7) * 4;
    float* d = &xs[b * NC + t0];
    d[0] = v.x; d[1] = v.y; d[2] = v.z; d[3] = v.w;
  }
  __syncthreads();

  const int b = tid;
  float acc[PWn];
  #pragma unroll
  for (int p = 0; p < PWn; ++p) acc[p] = Zl[p][0];
  for (int t = 0; t < LBn; ++t) {
    const float xval = xs[b * NC + t];
    #pragma unroll
    for (int p = 0; p < PWn; ++p) acc[p] += Zl[p][1 + t] * xval;
  }
  float4* op = (float4*)(out + (size_t)(b0 + b) * PWn);
  op[0] = make_float4(acc[0], acc[1], acc[2], acc[3]);
  op[1] = make_float4(acc[4], acc[5], acc[6], acc[7]);
  op[2] = make_float4(acc[8], acc[9], acc[10], acc[11]);
  op[3] = make_float4(acc[12], acc[13], acc[14], acc[15]);
}

extern "C" void kernel_launch(void* const* d_in, const int* in_sizes, int n_in,
                              void* d_out, int out_size, void* d_ws, size_t ws_size,
                              hipStream_t stream) {
  const float* x  = (const float*)d_in[0];
  const float* Fw = (const float*)d_in[1];
  const float* Fb = (const float*)d_in[2];
  const float* Hw = (const float*)d_in[3];
  const float* Hb = (const float*)d_in[4];
  const float* s0 = (const float*)d_in[5];
  const float* P0 = (const float*)d_in[6];
  const float* Q  = (const float*)d_in[7];
  const float* R  = (const float*)d_in[8];
  float* ws  = (float*)d_ws;
  float* out = (float*)d_out;

  kalmanA<<<2, 256, 0, stream>>>(Fw, Fb, Hw, Hb, s0, P0, Q, R, ws);
  kalmanB<<<16, 256, 0, stream>>>(x, ws, out);
}

// Round 2
// 347.678 us; speedup vs baseline: 1.1078x; 1.1078x over previous
//
#include <hip/hip_runtime.h>

// Kalman filter, reformulated:
//   out[b][p] = alpha_p + sum_t Z[p][t] * x[b][t]
// kalmanA block 0: shared 64x64 Riccati recursion (P) producing gains k_t,
//   with folded affine-state propagation V (col0 = bias, col 1+t = w_t).
// kalmanA block 1: prediction-phase row chains u_p, e_p.
// kalmanB: (4096x32)x(32x16) GEMM vs Z built from U,W.

constexpr int Hn  = 64;
constexpr int LBn = 32;
constexpr int PWn = 16;
constexpr int NC  = 33;   // V columns
constexpr int SF  = 68;   // FTs stride (dwords)
constexpr int SV  = 68;   // VT stride

// ws layout (floats): W is c-major: ws[WOFF_W + c*64 + i] = V[i][c]
constexpr int WOFF_W = 0;
constexpr int WOFF_U = NC * Hn;            // 2112
constexpr int WOFF_E = WOFF_U + PWn * Hn;  // 3136

// dword offset of 16B chunk c within swizzled row r (stride 64 dwords)
#define SWZ(r, c) ((((c) & 8) | (((c) & 7) ^ ((r) & 7))) << 2)

// acc[0..7] += aval * F-row-of-8 (two uniform float4 LDS reads)
#define MM_STEP(fbase, d, aval)                                 \
  {                                                             \
    const float4 b0 = *(const float4*)((fbase) + (d) * SF);     \
    const float4 b1 = *(const float4*)((fbase) + (d) * SF + 4); \
    acc[0] += (aval) * b0.x; acc[1] += (aval) * b0.y;           \
    acc[2] += (aval) * b0.z; acc[3] += (aval) * b0.w;           \
    acc[4] += (aval) * b1.x; acc[5] += (aval) * b1.y;           \
    acc[6] += (aval) * b1.z; acc[7] += (aval) * b1.w;           \
  }

__global__ __launch_bounds__(512) void kalmanA(
    const float* __restrict__ Fw, const float* __restrict__ Fb,
    const float* __restrict__ Hw, const float* __restrict__ Hb,
    const float* __restrict__ s0, const float* __restrict__ P0,
    const float* __restrict__ Qg, const float* __restrict__ Rg,
    float* __restrict__ ws) {
  const int tid  = threadIdx.x;
  const int lane = tid & 63;
  const int w    = tid >> 6;

  if (blockIdx.x == 1) {
    // ---- prediction-phase chains: u_p (row vectors), e_p (scalars) ----
    for (int pi = 0; pi < 2; ++pi) {
      const int p = pi ? (15 - w) : w;   // balanced: wave w does ~17 matvecs
      const int q = LBn + p;
      float r = Hw[q * Hn + lane];
      float eacc = 0.f;
      for (int s = 0; s <= p; ++s) {
        const int m = q - s;
        eacc += r * Fb[m * Hn + lane];
        const float* Fm = Fw + (size_t)m * Hn * Hn;
        float rn = 0.f;
        for (int j = 0; j < Hn; ++j)
          rn += __shfl(r, j, 64) * Fm[j * Hn + lane];
        r = rn;
      }
      #pragma unroll
      for (int o = 32; o >= 1; o >>= 1) eacc += __shfl_xor(eacc, o, 64);
      ws[WOFF_U + p * Hn + lane] = r;
      if (lane == 0) ws[WOFF_E + p] = eacc + Hb[q];
    }
    return;
  }

  // ---------------- block 0: shared P-recursion ----------------
  __shared__ float Pr[Hn * 64];        // P, row-major, chunk-swizzled
  __shared__ float Tt[Hn * 64];        // (P F^T)^T, row-major, swizzled
  __shared__ float FTs[Hn * SF];       // FTs[k][l] = F[l][k]
  __shared__ float VT[(NC + 1) * SV];  // VT[c][i] = V[i][c] (+1 pad row)
  __shared__ float red1[8 * 64], red2[8 * 64];
  __shared__ float kvs[64], hPl[64], hb2[LBn];

  const float R0 = Rg[0];
  const int l0 = w * 8;
  const int c0 = (w == 0) ? 0 : (5 + (w - 1) * 4);
  const int nc = (w == 0) ? 5 : 4;
  const int sl = tid >> 3, sk0 = (tid & 7) * 8;

  // ---- prologue ----
  {
    const int r = tid >> 3, k0 = (tid & 7) * 8;
    const float4 a0 = *(const float4*)(P0 + r * 64 + k0);
    const float4 a1 = *(const float4*)(P0 + r * 64 + k0 + 4);
    *(float4*)&Pr[r * 64 + SWZ(r, k0 >> 2)] = a0;
    *(float4*)&Pr[r * 64 + SWZ(r, (k0 >> 2) + 1)] = a1;
  }
  for (int idx = tid; idx < (NC + 1) * Hn; idx += 512) {
    const int c = idx >> 6, i = idx & 63;
    VT[c * SV + i] = (c == 0) ? s0[i] : 0.f;
  }
  #pragma unroll
  for (int pi = 0; pi < 4; ++pi) {   // hb2[t] = h_t . Fb_t + Hb_t
    const int t = w * 4 + pi;
    float sv = Hw[t * 64 + lane] * Fb[t * 64 + lane];
    #pragma unroll
    for (int o = 32; o >= 1; o >>= 1) sv += __shfl_xor(sv, o, 64);
    if (lane == 0) hb2[t] = sv + Hb[t];
  }
  {  // stage F_0 transposed
    const float* src = Fw + sl * 64 + sk0;
    const float4 a0 = *(const float4*)src;
    const float4 a1 = *(const float4*)(src + 4);
    FTs[(sk0 + 0) * SF + sl] = a0.x; FTs[(sk0 + 1) * SF + sl] = a0.y;
    FTs[(sk0 + 2) * SF + sl] = a0.z; FTs[(sk0 + 3) * SF + sl] = a0.w;
    FTs[(sk0 + 4) * SF + sl] = a1.x; FTs[(sk0 + 5) * SF + sl] = a1.y;
    FTs[(sk0 + 6) * SF + sl] = a1.z; FTs[(sk0 + 7) * SF + sl] = a1.w;
  }
  __syncthreads();

  for (int t = 0; t < LBn; ++t) {
    // ---- phase 1: prefetch-issue + mm1 + FV + q ----
    float st[8];
    if (t + 1 < LBn) {  // issue global loads early; LDS writes in phase 5
      const float* src = Fw + (size_t)(t + 1) * 4096 + sl * 64 + sk0;
      const float4 a0 = *(const float4*)src;
      const float4 a1 = *(const float4*)(src + 4);
      st[0] = a0.x; st[1] = a0.y; st[2] = a0.z; st[3] = a0.w;
      st[4] = a1.x; st[5] = a1.y; st[6] = a1.z; st[7] = a1.w;
    }
    {  // mm1: (P F^T)[lane][l0+cc] -> Tt rows l0.., elem lane
      float acc[8] = {0, 0, 0, 0, 0, 0, 0, 0};
      #pragma unroll 4
      for (int kc = 0; kc < 16; ++kc) {
        const float4 av = *(const float4*)&Pr[lane * 64 + SWZ(lane, kc)];
        const float* fb_ = &FTs[(kc * 4) * SF + l0];
        MM_STEP(fb_, 0, av.x) MM_STEP(fb_, 1, av.y)
        MM_STEP(fb_, 2, av.z) MM_STEP(fb_, 3, av.w)
      }
      #pragma unroll
      for (int cc = 0; cc < 8; ++cc) {
        const int r = l0 + cc;
        Tt[r * 64 + SWZ(r, lane >> 2) + (lane & 3)] = acc[cc];
      }
    }
    float vacc[5] = {0, 0, 0, 0, 0};
    #pragma unroll 2
    for (int jc = 0; jc < 16; ++jc) {  // FV[lane][c0+cc]
      const int j0 = jc * 4;
      const float a0 = FTs[(j0 + 0) * SF + lane];
      const float a1 = FTs[(j0 + 1) * SF + lane];
      const float a2 = FTs[(j0 + 2) * SF + lane];
      const float a3 = FTs[(j0 + 3) * SF + lane];
      #pragma unroll
      for (int cc = 0; cc < 5; ++cc) {
        const float4 vv = *(const float4*)&VT[(c0 + cc) * SV + j0];
        vacc[cc] += a0 * vv.x + a1 * vv.y + a2 * vv.z + a3 * vv.w;
      }
    }
    float qv[5];
    {
      const float hval = Hw[t * 64 + lane];
      #pragma unroll
      for (int cc = 0; cc < 5; ++cc) {
        float s = vacc[cc] * hval;
        #pragma unroll
        for (int o = 32; o >= 1; o >>= 1) s += __shfl_xor(s, o, 64);
        qv[cc] = s;
      }
    }
    __syncthreads();  // A: Tt ready

    // ---- phase 2: mm2 -> P_pred (+Q), hP partial ----
    {
      float acc[8] = {0, 0, 0, 0, 0, 0, 0, 0};
      #pragma unroll 4
      for (int jc = 0; jc < 16; ++jc) {
        const float4 av = *(const float4*)&Tt[lane * 64 + SWZ(lane, jc)];
        const float* fb_ = &FTs[(jc * 4) * SF + l0];
        MM_STEP(fb_, 0, av.x) MM_STEP(fb_, 1, av.y)
        MM_STEP(fb_, 2, av.z) MM_STEP(fb_, 3, av.w)
      }
      float hp = 0.f;
      const float* hrow = Hw + t * 64;
      #pragma unroll
      for (int cc = 0; cc < 8; ++cc) {
        const int r = l0 + cc;
        const float v2 = acc[cc] + Qg[r * 64 + lane];
        hp += hrow[r] * v2;
        Pr[r * 64 + SWZ(r, lane >> 2) + (lane & 3)] = v2;
      }
      red2[w * 64 + lane] = hp;
    }
    __syncthreads();  // B: P_pred ready

    // ---- phase 3: num partials ----
    {
      const float4 a0 = *(const float4*)&Pr[lane * 64 + SWZ(lane, 2 * w)];
      const float4 a1 = *(const float4*)&Pr[lane * 64 + SWZ(lane, 2 * w + 1)];
      const float4 h0 = *(const float4*)(Hw + t * 64 + w * 8);
      const float4 h1 = *(const float4*)(Hw + t * 64 + w * 8 + 4);
      red1[w * 64 + lane] =
          a0.x * h0.x + a0.y * h0.y + a0.z * h0.z + a0.w * h0.w +
          a1.x * h1.x + a1.y * h1.y + a1.z * h1.z + a1.w * h1.w;
    }
    __syncthreads();  // C

    // ---- phase 4: wave 0 finalizes k ----
    if (w == 0) {
      float num = 0.f, hp = 0.f;
      #pragma unroll
      for (int u = 0; u < 8; ++u) {
        num += red1[u * 64 + lane];
        hp  += red2[u * 64 + lane];
      }
      hPl[lane] = hp;
      float sv = Hw[t * 64 + lane] * num;
      #pragma unroll
      for (int o = 32; o >= 1; o >>= 1) sv += __shfl_xor(sv, o, 64);
      kvs[lane] = num / (sv + R0);
    }
    __syncthreads();  // D: kvs, hPl ready

    // ---- phase 5: stage F_{t+1}, rank-1 P update, V update ----
    if (t + 1 < LBn) {
      FTs[(sk0 + 0) * SF + sl] = st[0]; FTs[(sk0 + 1) * SF + sl] = st[1];
      FTs[(sk0 + 2) * SF + sl] = st[2]; FTs[(sk0 + 3) * SF + sl] = st[3];
      FTs[(sk0 + 4) * SF + sl] = st[4]; FTs[(sk0 + 5) * SF + sl] = st[5];
      FTs[(sk0 + 6) * SF + sl] = st[6]; FTs[(sk0 + 7) * SF + sl] = st[7];
    }
    {
      const float hp = hPl[lane];
      #pragma unroll
      for (int u = 0; u < 8; ++u) {
        const int i = l0 + u;
        Pr[i * 64 + SWZ(i, lane >> 2) + (lane & 3)] -= kvs[i] * hp;
      }
      const float kv = kvs[lane];
      #pragma unroll
      for (int cc = 0; cc < 5; ++cc) {
        if (cc < nc) {
          const int c = c0 + cc;
          float val = vacc[cc] - kv * qv[cc];
          if (c == 0) val += Fb[t * 64 + lane] - kv * hb2[t];
          if (c == t + 1) val = kv;
          VT[c * SV + lane] = val;
        }
      }
    }
    __syncthreads();  // E: end of step
  }

  for (int idx = tid; idx < NC * Hn; idx += 512) {
    const int c = idx >> 6, i = idx & 63;
    ws[WOFF_W + idx] = VT[c * SV + i];
  }
}

__global__ __launch_bounds__(256) void kalmanB(
    const float* __restrict__ x, const float* __restrict__ ws,
    float* __restrict__ out) {
  __shared__ float Zl[PWn][NC + 1];
  __shared__ float xs[256 * NC];
  const int tid = threadIdx.x;
  const int b0  = blockIdx.x * 256;

  for (int idx = tid; idx < PWn * NC; idx += 256) {
    const int p = idx / NC, c = idx % NC;
    const float* Up = ws + WOFF_U + p * Hn;
    const float* Wc = ws + WOFF_W + c * Hn;
    float acc = 0.f;
    for (int i = 0; i < Hn; ++i) acc += Up[i] * Wc[i];
    if (c == 0) acc += ws[WOFF_E + p];
    Zl[p][c] = acc;
  }
  const float4* xv = (const float4*)(x + (size_t)b0 * LBn);
  #pragma unroll
  for (int r = 0; r < 8; ++r) {
    const int fi = tid + 256 * r;
    const float4 v = xv[fi];
    const int b  = fi >> 3;
    const int t0 = (fi & 7) * 4;
    float* d = &xs[b * NC + t0];
    d[0] = v.x; d[1] = v.y; d[2] = v.z; d[3] = v.w;
  }
  __syncthreads();

  const int b = tid;
  float acc[PWn];
  #pragma unroll
  for (int p = 0; p < PWn; ++p) acc[p] = Zl[p][0];
  for (int t = 0; t < LBn; ++t) {
    const float xval = xs[b * NC + t];
    #pragma unroll
    for (int p = 0; p < PWn; ++p) acc[p] += Zl[p][1 + t] * xval;
  }
  float4* op = (float4*)(out + (size_t)(b0 + b) * PWn);
  op[0] = make_float4(acc[0], acc[1], acc[2], acc[3]);
  op[1] = make_float4(acc[4], acc[5], acc[6], acc[7]);
  op[2] = make_float4(acc[8], acc[9], acc[10], acc[11]);
  op[3] = make_float4(acc[12], acc[13], acc[14], acc[15]);
}

extern "C" void kernel_launch(void* const* d_in, const int* in_sizes, int n_in,
                              void* d_out, int out_size, void* d_ws, size_t ws_size,
                              hipStream_t stream) {
  const float* x  = (const float*)d_in[0];
  const float* Fw = (const float*)d_in[1];
  const float* Fb = (const float*)d_in[2];
  const float* Hw = (const float*)d_in[3];
  const float* Hb = (const float*)d_in[4];
  const float* s0 = (const float*)d_in[5];
  const float* P0 = (const float*)d_in[6];
  const float* Q  = (const float*)d_in[7];
  const float* R  = (const float*)d_in[8];
  float* ws  = (float*)d_ws;
  float* out = (float*)d_out;

  kalmanA<<<2, 512, 0, stream>>>(Fw, Fb, Hw, Hb, s0, P0, Q, R, ws);
  kalmanB<<<16, 256, 0, stream>>>(x, ws, out);
}

// Round 3
// 152.812 us; speedup vs baseline: 2.5205x; 2.2752x over previous
//
#include <hip/hip_runtime.h>

// Kalman filter, reformulated:
//   out[b][p] = alpha_p + sum_t Z[p][t] * x[b][t]
// kalmanA block 0: shared 64x64 Riccati recursion producing gains k_t only,
//   via split-f16 MFMA (v_mfma_f32_16x16x16f16) with fragment-major LDS.
// kalmanA block 1: prediction-phase row chains u_p, e_p (fp32 VALU).
// kalmanC: 33 independent V-columns (col0 bias chain + w_t chains), fp32.
// kalmanB: (4096x32)x(32x16) GEMM vs Z built from U,W.

constexpr int Hn  = 64;
constexpr int LBn = 32;
constexpr int PWn = 16;
constexpr int NC  = 33;   // V columns

// ws layout (floats): W c-major [33][64], U [16][64], E [16], K [32][64]
constexpr int WOFF_W = 0;
constexpr int WOFF_U = NC * Hn;            // 2112
constexpr int WOFF_E = WOFF_U + PWn * Hn;  // 3136
constexpr int WOFF_K = WOFF_E + PWn;       // 3152

typedef float  f32x4 __attribute__((ext_vector_type(4)));
typedef _Float16 f16x4 __attribute__((ext_vector_type(4)));
typedef _Float16 f16x8 __attribute__((ext_vector_type(8)));

#define MFMA16(a, b, c) __builtin_amdgcn_mfma_f32_16x16x16f16((a), (b), (c), 0, 0, 0)

__global__ __launch_bounds__(512) void kalmanA(
    const float* __restrict__ Fw, const float* __restrict__ Fb,
    const float* __restrict__ Hw, const float* __restrict__ Hb,
    const float* __restrict__ s0, const float* __restrict__ P0,
    const float* __restrict__ Qg, const float* __restrict__ Rg,
    float* __restrict__ ws) {
  const int tid  = threadIdx.x;
  const int lane = tid & 63;
  const int w    = tid >> 6;

  if (blockIdx.x == 1) {
    // ---- prediction-phase chains: u_p (row vectors), e_p (scalars) ----
    for (int pi = 0; pi < 2; ++pi) {
      const int p = pi ? (15 - w) : w;
      const int q = LBn + p;
      float r = Hw[q * Hn + lane];
      float eacc = 0.f;
      for (int s = 0; s <= p; ++s) {
        const int m = q - s;
        eacc += r * Fb[m * Hn + lane];
        const float* Fm = Fw + (size_t)m * Hn * Hn;
        float rn = 0.f;
        for (int j = 0; j < Hn; ++j)
          rn += __shfl(r, j, 64) * Fm[j * Hn + lane];
        r = rn;
      }
      #pragma unroll
      for (int o = 32; o >= 1; o >>= 1) eacc += __shfl_xor(eacc, o, 64);
      ws[WOFF_U + p * Hn + lane] = r;
      if (lane == 0) ws[WOFF_E + p] = eacc + Hb[q];
    }
    return;
  }

  // ---------------- block 0: P/k recursion with split-f16 MFMA ----------------
  // Ffrag[tr*4+kc][lane][0..3]=hi, [4..7]=lo*2048 of F[(l&15)+16tr][16kc+4*(l>>4)+j]
  __shared__ _Float16 Ffrag[16][65][8];
  __shared__ float    Tfrag[16][64][4];   // T C/D frags, packed (lane-linear b128)
  __shared__ float    Pfrag[16][64][5];   // Ppred C/D frags, pad-5
  __shared__ float    nred[2][64], mred[4][64], hv[64];

  const float R0 = Rg[0];
  const int l15 = lane & 15, g = lane >> 4;
  const int ti = w >> 1, half = w & 1;
  const int lp0 = 16 * (l15 >> 2) + 4 * g;
  const int rg  = l15 & 3;
  const int sr = tid >> 3, sc0 = (tid & 7) * 8;
  const int fi = (sr >> 4) * 4 + (sc0 >> 4);
  const int L0 = (sr & 15) + 16 * ((sc0 >> 2) & 3);
  float* kws = ws + WOFF_K;

  // ---- prologue ----
  float qf[2][4];
  #pragma unroll
  for (int s2 = 0; s2 < 2; ++s2)
    #pragma unroll
    for (int reg = 0; reg < 4; ++reg)
      qf[s2][reg] = Qg[(16 * ti + 4 * g + reg) * 64 + l15 + 16 * (2 * half + s2)];

  #pragma unroll
  for (int u = 0; u < 8; ++u) {   // P0 -> Pfrag
    const int cc = sc0 + u;
    Pfrag[(sr >> 4) * 4 + (cc >> 4)][16 * ((sr & 15) >> 2) + (cc & 15)][sr & 3] =
        P0[sr * 64 + cc];
  }
  f32x4 fpa = *(const f32x4*)(Fw + sr * 64 + sc0);
  f32x4 fpb = *(const f32x4*)(Fw + sr * 64 + sc0 + 4);
  __syncthreads();

  float kv = 0.f, mr = 0.f;
  for (int t = 0; t < LBn; ++t) {
    // ---- phase C: finalize k_{t-1}, cvt A-frags (rank-1 fused), stage F_t ----
    if (t > 0) {
      const float n = nred[0][lane] + nred[1][lane];
      mr = mred[0][lane] + mred[1][lane] + mred[2][lane] + mred[3][lane];
      float s = hv[lane] * n;
      #pragma unroll
      for (int o = 32; o >= 1; o >>= 1) s += __shfl_xor(s, o, 64);
      kv = n / (s + R0);
      if (w == 0) kws[(t - 1) * 64 + lane] = kv;
    } else { kv = 0.f; mr = 0.f; }

    const float kr = __shfl(kv, l15 + 16 * ti, 64);
    f16x4 Ah[4], Al[4];
    #pragma unroll
    for (int kc = 0; kc < 4; ++kc) {
      #pragma unroll
      for (int j = 0; j < 4; ++j) {
        const float mcol = __shfl(mr, 16 * kc + 4 * g + j, 64);
        const float pv = Pfrag[ti * 4 + kc][lp0 + j][rg] - kr * mcol;
        const _Float16 hi_ = (_Float16)pv;
        Ah[kc][j] = hi_;
        Al[kc][j] = (_Float16)((pv - (float)hi_) * 2048.0f);
      }
    }
    {  // stage F_t fragments from prefetched regs
      f16x8 pa, pb;
      #pragma unroll
      for (int u = 0; u < 4; ++u) {
        const _Float16 ha = (_Float16)fpa[u];
        pa[u] = ha; pa[4 + u] = (_Float16)((fpa[u] - (float)ha) * 2048.0f);
        const _Float16 hb = (_Float16)fpb[u];
        pb[u] = hb; pb[4 + u] = (_Float16)((fpb[u] - (float)hb) * 2048.0f);
      }
      *(f16x8*)&Ffrag[fi][L0][0]      = pa;
      *(f16x8*)&Ffrag[fi][L0 + 16][0] = pb;
    }
    __syncthreads();  // B3

    // ---- phase A: mm1  T = P_work * F_t^T ----
    if (t + 1 < LBn) {
      fpa = *(const f32x4*)(Fw + (size_t)(t + 1) * 4096 + sr * 64 + sc0);
      fpb = *(const f32x4*)(Fw + (size_t)(t + 1) * 4096 + sr * 64 + sc0 + 4);
    }
    if (w == 0) hv[lane] = Hw[t * 64 + lane];
    #pragma unroll
    for (int s2 = 0; s2 < 2; ++s2) {
      const int tj = 2 * half + s2;
      f32x4 accm = {0.f, 0.f, 0.f, 0.f}, accc = {0.f, 0.f, 0.f, 0.f};
      #pragma unroll
      for (int kc = 0; kc < 4; ++kc) {
        const f16x8 bv = *(const f16x8*)&Ffrag[tj * 4 + kc][lane][0];
        const f16x4 bh = __builtin_shufflevector(bv, bv, 0, 1, 2, 3);
        const f16x4 bl = __builtin_shufflevector(bv, bv, 4, 5, 6, 7);
        accm = MFMA16(Ah[kc], bh, accm);
        accc = MFMA16(Ah[kc], bl, accc);
        accc = MFMA16(Al[kc], bh, accc);
      }
      const f32x4 outv = accm + accc * (1.0f / 2048.0f);
      *(f32x4*)&Tfrag[ti * 4 + tj][lane][0] = outv;
    }
    __syncthreads();  // B1

    // ---- phase B: mm2  Ppred = F_t * T + Q, reductions ----
    f16x4 FAh[4], FAl[4];
    #pragma unroll
    for (int kc = 0; kc < 4; ++kc) {
      const f16x8 av = *(const f16x8*)&Ffrag[ti * 4 + kc][lane][0];
      FAh[kc] = __builtin_shufflevector(av, av, 0, 1, 2, 3);
      FAl[kc] = __builtin_shufflevector(av, av, 4, 5, 6, 7);
    }
    f32x4 pout[2];
    #pragma unroll
    for (int s2 = 0; s2 < 2; ++s2) {
      const int tj = 2 * half + s2;
      f32x4 accm = {0.f, 0.f, 0.f, 0.f}, accc = {0.f, 0.f, 0.f, 0.f};
      #pragma unroll
      for (int kc = 0; kc < 4; ++kc) {
        const f32x4 tv = *(const f32x4*)&Tfrag[kc * 4 + tj][lane][0];
        f16x4 th, tl;
        #pragma unroll
        for (int j = 0; j < 4; ++j) {
          const _Float16 hi_ = (_Float16)tv[j];
          th[j] = hi_;
          tl[j] = (_Float16)((tv[j] - (float)hi_) * 2048.0f);
        }
        accm = MFMA16(FAh[kc], th, accm);
        accc = MFMA16(FAh[kc], tl, accc);
        accc = MFMA16(FAl[kc], th, accc);
      }
      pout[s2] = accm + accc * (1.0f / 2048.0f);
      #pragma unroll
      for (int reg = 0; reg < 4; ++reg) {
        pout[s2][reg] += qf[s2][reg];
        Pfrag[ti * 4 + tj][lane][reg] = pout[s2][reg];
      }
    }
    {
      const float hc0 = hv[l15 + 16 * (2 * half)];
      const float hc1 = hv[l15 + 16 * (2 * half + 1)];
      float np[4];
      #pragma unroll
      for (int reg = 0; reg < 4; ++reg)
        np[reg] = pout[0][reg] * hc0 + pout[1][reg] * hc1;
      #pragma unroll
      for (int m = 1; m <= 8; m <<= 1)
        #pragma unroll
        for (int reg = 0; reg < 4; ++reg)
          np[reg] += __shfl_xor(np[reg], m, 64);
      if (l15 == 0) {
        #pragma unroll
        for (int reg = 0; reg < 4; ++reg)
          nred[half][16 * ti + 4 * g + reg] = np[reg];
      }
      float hr[4];
      #pragma unroll
      for (int reg = 0; reg < 4; ++reg) hr[reg] = hv[16 * ti + 4 * g + reg];
      float mp0 = 0.f, mp1 = 0.f;
      #pragma unroll
      for (int reg = 0; reg < 4; ++reg) {
        mp0 += pout[0][reg] * hr[reg];
        mp1 += pout[1][reg] * hr[reg];
      }
      mp0 += __shfl_xor(mp0, 16, 64); mp0 += __shfl_xor(mp0, 32, 64);
      mp1 += __shfl_xor(mp1, 16, 64); mp1 += __shfl_xor(mp1, 32, 64);
      if (g == 0) {
        mred[ti][l15 + 16 * (2 * half)]     = mp0;
        mred[ti][l15 + 16 * (2 * half + 1)] = mp1;
      }
    }
    __syncthreads();  // B2
  }

  // finalize k_31
  {
    const float n = nred[0][lane] + nred[1][lane];
    float s = hv[lane] * n;
    #pragma unroll
    for (int o = 32; o >= 1; o >>= 1) s += __shfl_xor(s, o, 64);
    if (w == 0) kws[31 * 64 + lane] = n / (s + R0);
  }
}

// ---- V-columns: col 0 = bias chain, col c (1..32) = w_{c-1} chain ----
__global__ __launch_bounds__(64) void kalmanC(
    const float* __restrict__ Fw, const float* __restrict__ Fb,
    const float* __restrict__ Hw, const float* __restrict__ Hb,
    const float* __restrict__ s0, float* __restrict__ ws) {
  const int c = blockIdx.x;
  const int lane = threadIdx.x;
  const float* kws = ws + WOFF_K;
  if (c == 32) {  // w_31 = k_31 (no propagation)
    ws[WOFF_W + 32 * 64 + lane] = kws[31 * 64 + lane];
    return;
  }
  __shared__ float vbuf[64];
  float v; int t0;
  if (c == 0) { v = s0[lane]; t0 = 0; }
  else        { v = kws[(c - 1) * 64 + lane]; t0 = c; }

  f32x4 fn[16];
  {
    const float* Fr = Fw + (size_t)t0 * 4096 + lane * 64;
    #pragma unroll
    for (int jc = 0; jc < 16; ++jc) fn[jc] = *(const f32x4*)(Fr + jc * 4);
  }
  for (int t = t0; t < 32; ++t) {
    vbuf[lane] = v;
    __syncthreads();
    f32x4 fc[16];
    #pragma unroll
    for (int jc = 0; jc < 16; ++jc) fc[jc] = fn[jc];
    if (t + 1 < 32) {
      const float* Fr = Fw + (size_t)(t + 1) * 4096 + lane * 64;
      #pragma unroll
      for (int jc = 0; jc < 16; ++jc) fn[jc] = *(const f32x4*)(Fr + jc * 4);
    }
    float vp = (c == 0) ? Fb[t * 64 + lane] : 0.f;
    #pragma unroll
    for (int jc = 0; jc < 16; ++jc) {
      const f32x4 vb = *(const f32x4*)&vbuf[jc * 4];
      vp += fc[jc].x * vb.x + fc[jc].y * vb.y + fc[jc].z * vb.z + fc[jc].w * vb.w;
    }
    float hvp = Hw[t * 64 + lane] * vp;
    #pragma unroll
    for (int o = 32; o >= 1; o >>= 1) hvp += __shfl_xor(hvp, o, 64);
    if (c == 0) hvp += Hb[t];
    v = vp - kws[t * 64 + lane] * hvp;
    __syncthreads();
  }
  ws[WOFF_W + c * 64 + lane] = v;
}

__global__ __launch_bounds__(256) void kalmanB(
    const float* __restrict__ x, const float* __restrict__ ws,
    float* __restrict__ out) {
  __shared__ float Zl[PWn][NC + 1];
  __shared__ float xs[256 * NC];
  const int tid = threadIdx.x;
  const int b0  = blockIdx.x * 256;

  for (int idx = tid; idx < PWn * NC; idx += 256) {
    const int p = idx / NC, c = idx % NC;
    const float* Up = ws + WOFF_U + p * Hn;
    const float* Wc = ws + WOFF_W + c * Hn;
    float acc = 0.f;
    for (int i = 0; i < Hn; ++i) acc += Up[i] * Wc[i];
    if (c == 0) acc += ws[WOFF_E + p];
    Zl[p][c] = acc;
  }
  const float4* xv = (const float4*)(x + (size_t)b0 * LBn);
  #pragma unroll
  for (int r = 0; r < 8; ++r) {
    const int fi = tid + 256 * r;
    const float4 v = xv[fi];
    const int b  = fi >> 3;
    const int t0 = (fi & 7) * 4;
    float* d = &xs[b * NC + t0];
    d[0] = v.x; d[1] = v.y; d[2] = v.z; d[3] = v.w;
  }
  __syncthreads();

  const int b = tid;
  float acc[PWn];
  #pragma unroll
  for (int p = 0; p < PWn; ++p) acc[p] = Zl[p][0];
  for (int t = 0; t < LBn; ++t) {
    const float xval = xs[b * NC + t];
    #pragma unroll
    for (int p = 0; p < PWn; ++p) acc[p] += Zl[p][1 + t] * xval;
  }
  float4* op = (float4*)(out + (size_t)(b0 + b) * PWn);
  op[0] = make_float4(acc[0], acc[1], acc[2], acc[3]);
  op[1] = make_float4(acc[4], acc[5], acc[6], acc[7]);
  op[2] = make_float4(acc[8], acc[9], acc[10], acc[11]);
  op[3] = make_float4(acc[12], acc[13], acc[14], acc[15]);
}

extern "C" void kernel_launch(void* const* d_in, const int* in_sizes, int n_in,
                              void* d_out, int out_size, void* d_ws, size_t ws_size,
                              hipStream_t stream) {
  const float* x  = (const float*)d_in[0];
  const float* Fw = (const float*)d_in[1];
  const float* Fb = (const float*)d_in[2];
  const float* Hw = (const float*)d_in[3];
  const float* Hb = (const float*)d_in[4];
  const float* s0 = (const float*)d_in[5];
  const float* P0 = (const float*)d_in[6];
  const float* Q  = (const float*)d_in[7];
  const float* R  = (const float*)d_in[8];
  float* ws  = (float*)d_ws;
  float* out = (float*)d_out;

  kalmanA<<<2, 512, 0, stream>>>(Fw, Fb, Hw, Hb, s0, P0, Q, R, ws);
  kalmanC<<<33, 64, 0, stream>>>(Fw, Fb, Hw, Hb, s0, ws);
  kalmanB<<<16, 256, 0, stream>>>(x, ws, out);
}

// Round 4
// 127.684 us; speedup vs baseline: 3.0166x; 1.1968x over previous
//
#include <hip/hip_runtime.h>

// Kalman filter, reformulated:  out[b][p] = alpha_p + sum_t Z[p][t] x[b][t]
// Single fused kernel, 15 blocks x 512:
//   block 0    : shared 64x64 Riccati recursion -> gains k_t (split-f16 MFMA,
//                2 barriers/step, DPP reductions), published via tagged atomics
//   block 1    : prediction-phase row chains u_p, e_p
//   blocks 2-6 : 33 V-column chains (1 wave each), consume k_t as published
//   blocks 7-14: output GEMM; spin on tagged U/W/E, build Z, compute out
// ws (u64): KP[32*64] k_t (tag t+1) | WP[33*64] (tag 1) | UP[16*64] | EP[16]

constexpr int KP_OFF = 0;
constexpr int WP_OFF = 2048;
constexpr int UP_OFF = 4160;
constexpr int EP_OFF = 5184;
constexpr int WS_U64 = 5200;

typedef float    f32x4 __attribute__((ext_vector_type(4)));
typedef _Float16 f16x4 __attribute__((ext_vector_type(4)));
typedef _Float16 f16x8 __attribute__((ext_vector_type(8)));

#define MFMA16(a, b, c) __builtin_amdgcn_mfma_f32_16x16x16f16((a), (b), (c), 0, 0, 0)

template <int CTRL>
__device__ __forceinline__ float dpp_add(float x) {
  int v = __builtin_amdgcn_update_dpp(0, __builtin_bit_cast(int, x), CTRL, 0xf, 0xf, true);
  return x + __builtin_bit_cast(float, v);
}
__device__ __forceinline__ float sum16(float x) {  // butterfly within 16-lane rows
  x = dpp_add<0xB1>(x);   // quad_perm xor1
  x = dpp_add<0x4E>(x);   // quad_perm xor2
  x = dpp_add<0x141>(x);  // row_half_mirror (xor4)
  x = dpp_add<0x140>(x);  // row_mirror (xor8)
  return x;
}
__device__ __forceinline__ float sum64(float x) {
  x = sum16(x);
  x += __shfl_xor(x, 16, 64);
  x += __shfl_xor(x, 32, 64);
  return x;
}

__device__ __forceinline__ float spin_read(const unsigned long long* p, unsigned tag) {
  unsigned long long v = 0;
  for (int it = 0; it < (1 << 22); ++it) {
    v = __hip_atomic_load(p, __ATOMIC_RELAXED, __HIP_MEMORY_SCOPE_AGENT);
    if ((unsigned)(v >> 32) == tag) break;
  }
  union { unsigned u; float f; } cv; cv.u = (unsigned)v;
  return cv.f;
}
__device__ __forceinline__ void pub_write(unsigned long long* p, unsigned tag, float x) {
  union { float f; unsigned u; } cv; cv.f = x;
  __hip_atomic_store(p, ((unsigned long long)tag << 32) | cv.u,
                     __ATOMIC_RELAXED, __HIP_MEMORY_SCOPE_AGENT);
}

__global__ __launch_bounds__(512) void kalman_fused(
    const float* __restrict__ Fw, const float* __restrict__ Fb,
    const float* __restrict__ Hw, const float* __restrict__ Hb,
    const float* __restrict__ s0, const float* __restrict__ P0,
    const float* __restrict__ Qg, const float* __restrict__ Rg,
    const float* __restrict__ x, float* __restrict__ out,
    unsigned long long* __restrict__ ws) {
  __shared__ __align__(16) char smem[55040];
  const int tid  = threadIdx.x;
  const int lane = tid & 63;
  const int w    = tid >> 6;
  const int blk  = blockIdx.x;
  unsigned long long* kp = ws + KP_OFF;
  unsigned long long* wp = ws + WP_OFF;
  unsigned long long* up = ws + UP_OFF;
  unsigned long long* ep = ws + EP_OFF;

  if (blk == 0) {
    // ================= P/k Riccati recursion (split-f16 MFMA) =================
    _Float16* FF  = (_Float16*)smem;            // [16][65][8]  F frags (hi|lo)
    _Float16* TF  = (_Float16*)(smem + 16640);  // [16][64][8]  T frags (hi|lo)
    float*    PF  = (float*)(smem + 33024);     // [16][64][5]  Ppred C-frags
    float*    nred = (float*)(smem + 53504);    // [2][64]
    float*    mred = (float*)(smem + 54016);    // [4][64]

    const int l15 = lane & 15, g = lane >> 4;
    const int ti = w >> 1, half = w & 1;
    const int lp0 = 16 * (l15 >> 2) + 4 * g;
    const int rg  = l15 & 3;
    const int sr = tid >> 3, sc0 = (tid & 7) * 8;
    const int fi = (sr >> 4) * 4 + (sc0 >> 4);
    const int L0 = (sr & 15) + 16 * ((sc0 >> 2) & 3);
    const float R0 = Rg[0];

    auto FFp = [&](int f, int l) { return FF + (f * 65 + l) * 8; };
    auto TFp = [&](int f, int l) { return TF + (f * 64 + l) * 8; };
    auto PFi = [&](int f, int l, int r) { return (f * 64 + l) * 5 + r; };

    auto stageF = [&](f32x4 a, f32x4 b) {
      f16x8 pa, pb;
      #pragma unroll
      for (int u = 0; u < 4; ++u) {
        const _Float16 ha = (_Float16)a[u];
        pa[u] = ha; pa[4 + u] = (_Float16)((a[u] - (float)ha) * 2048.0f);
        const _Float16 hb = (_Float16)b[u];
        pb[u] = hb; pb[4 + u] = (_Float16)((b[u] - (float)hb) * 2048.0f);
      }
      *(f16x8*)FFp(fi, L0)      = pa;
      *(f16x8*)FFp(fi, L0 + 16) = pb;
    };

    // ---- prologue ----
    float qf0[4], qf1[4];
    #pragma unroll
    for (int reg = 0; reg < 4; ++reg) {
      qf0[reg] = Qg[(16 * ti + 4 * g + reg) * 64 + 16 * (2 * half) + l15];
      qf1[reg] = Qg[(16 * ti + 4 * g + reg) * 64 + 16 * (2 * half + 1) + l15];
    }
    #pragma unroll
    for (int u = 0; u < 8; ++u) {
      const int cc = sc0 + u;
      PF[PFi((sr >> 4) * 4 + (cc >> 4), 16 * ((sr & 15) >> 2) + (cc & 15), sr & 3)] =
          P0[sr * 64 + cc];
    }
    f32x4 fpa = *(const f32x4*)(Fw + sr * 64 + sc0);
    f32x4 fpb = *(const f32x4*)(Fw + sr * 64 + sc0 + 4);
    stageF(fpa, fpb);
    float hcur = Hw[lane], hprev = 0.f, hnext = 0.f;
    __syncthreads();

    for (int t = 0; t < 32; ++t) {
      // ---- phase 1: k-finalize + A-cvt(rank-1 fused) + mm1 ----
      float kv = 0.f, mr = 0.f;
      if (t > 0) {
        const float n = nred[lane] + nred[64 + lane];
        mr = mred[lane] + mred[64 + lane] + mred[128 + lane] + mred[192 + lane];
        const float s = sum64(hprev * n);
        kv = n / (s + R0);
        if (w == 0) pub_write(&kp[(t - 1) * 64 + lane], (unsigned)t, kv);
      }
      if (t + 1 < 32) {  // prefetch next F, h
        fpa = *(const f32x4*)(Fw + (size_t)(t + 1) * 4096 + sr * 64 + sc0);
        fpb = *(const f32x4*)(Fw + (size_t)(t + 1) * 4096 + sr * 64 + sc0 + 4);
        hnext = Hw[(t + 1) * 64 + lane];
      }
      const float kr = __shfl(kv, l15 + 16 * ti, 64);
      f16x4 Ah[4], Al[4];
      #pragma unroll
      for (int kc = 0; kc < 4; ++kc) {
        #pragma unroll
        for (int j = 0; j < 4; ++j) {
          const float mcol = __shfl(mr, 16 * kc + 4 * g + j, 64);
          const float pv = PF[PFi(ti * 4 + kc, lp0 + j, rg)] - kr * mcol;
          const _Float16 hi_ = (_Float16)pv;
          Ah[kc][j] = hi_;
          Al[kc][j] = (_Float16)((pv - (float)hi_) * 2048.0f);
        }
      }
      f16x4 FAh[4], FAl[4];  // pre-read mm2 A-operand (F) before barrier A
      #pragma unroll
      for (int kc = 0; kc < 4; ++kc) {
        const f16x8 av = *(const f16x8*)FFp(ti * 4 + kc, lane);
        FAh[kc] = __builtin_shufflevector(av, av, 0, 1, 2, 3);
        FAl[kc] = __builtin_shufflevector(av, av, 4, 5, 6, 7);
      }
      #pragma unroll
      for (int s2 = 0; s2 < 2; ++s2) {
        const int tj = 2 * half + s2;
        f32x4 am = {0.f, 0.f, 0.f, 0.f}, a1 = {0.f, 0.f, 0.f, 0.f}, a2 = {0.f, 0.f, 0.f, 0.f};
        #pragma unroll
        for (int kc = 0; kc < 4; ++kc) {
          const f16x8 bv = *(const f16x8*)FFp(tj * 4 + kc, lane);
          const f16x4 bh = __builtin_shufflevector(bv, bv, 0, 1, 2, 3);
          const f16x4 bl = __builtin_shufflevector(bv, bv, 4, 5, 6, 7);
          am = MFMA16(Ah[kc], bh, am);
          a1 = MFMA16(Ah[kc], bl, a1);
          a2 = MFMA16(Al[kc], bh, a2);
        }
        const f32x4 outv = am + (a1 + a2) * (1.0f / 2048.0f);
        f16x8 tv;
        #pragma unroll
        for (int j = 0; j < 4; ++j) {
          const _Float16 hi_ = (_Float16)outv[j];
          tv[j] = hi_;
          tv[4 + j] = (_Float16)((outv[j] - (float)hi_) * 2048.0f);
        }
        *(f16x8*)TFp(ti * 4 + tj, lane) = tv;
      }
      __syncthreads();  // A

      // ---- phase 2: stage F_{t+1} + mm2 + reductions ----
      if (t + 1 < 32) stageF(fpa, fpb);
      f32x4 pout[2];
      #pragma unroll
      for (int s2 = 0; s2 < 2; ++s2) {
        const int tj = 2 * half + s2;
        f32x4 am = {0.f, 0.f, 0.f, 0.f}, a1 = {0.f, 0.f, 0.f, 0.f}, a2 = {0.f, 0.f, 0.f, 0.f};
        #pragma unroll
        for (int kc = 0; kc < 4; ++kc) {
          const f16x8 bv = *(const f16x8*)TFp(kc * 4 + tj, lane);
          const f16x4 bh = __builtin_shufflevector(bv, bv, 0, 1, 2, 3);
          const f16x4 bl = __builtin_shufflevector(bv, bv, 4, 5, 6, 7);
          am = MFMA16(FAh[kc], bh, am);
          a1 = MFMA16(FAh[kc], bl, a1);
          a2 = MFMA16(FAl[kc], bh, a2);
        }
        pout[s2] = am + (a1 + a2) * (1.0f / 2048.0f);
        #pragma unroll
        for (int reg = 0; reg < 4; ++reg) {
          pout[s2][reg] += (s2 ? qf1[reg] : qf0[reg]);
          PF[PFi(ti * 4 + tj, lane, reg)] = pout[s2][reg];
        }
      }
      const float hcA = __shfl(hcur, 16 * (2 * half) + l15, 64);
      const float hcB = __shfl(hcur, 16 * (2 * half + 1) + l15, 64);
      float hr[4];
      #pragma unroll
      for (int reg = 0; reg < 4; ++reg) hr[reg] = __shfl(hcur, 16 * ti + 4 * g + reg, 64);
      #pragma unroll
      for (int reg = 0; reg < 4; ++reg) {
        float np = pout[0][reg] * hcA + pout[1][reg] * hcB;
        np = sum16(np);
        if (l15 == 0) nred[half * 64 + 16 * ti + 4 * g + reg] = np;
      }
      float mp0 = 0.f, mp1 = 0.f;
      #pragma unroll
      for (int reg = 0; reg < 4; ++reg) {
        mp0 += pout[0][reg] * hr[reg];
        mp1 += pout[1][reg] * hr[reg];
      }
      mp0 += __shfl_xor(mp0, 16, 64); mp0 += __shfl_xor(mp0, 32, 64);
      mp1 += __shfl_xor(mp1, 16, 64); mp1 += __shfl_xor(mp1, 32, 64);
      if (g == 0) {
        mred[ti * 64 + 16 * (2 * half) + l15]     = mp0;
        mred[ti * 64 + 16 * (2 * half + 1) + l15] = mp1;
      }
      __syncthreads();  // B
      hprev = hcur; hcur = hnext;
    }
    {  // finalize k_31
      const float n = nred[lane] + nred[64 + lane];
      const float s = sum64(hprev * n);
      if (w == 0) pub_write(&kp[31 * 64 + lane], 32u, n / (s + R0));
    }
    return;
  }

  if (blk == 1) {
    // ================= prediction-phase chains u_p, e_p =================
    for (int pi = 0; pi < 2; ++pi) {
      const int p = pi ? (15 - w) : w;
      const int q = 32 + p;
      float r = Hw[q * 64 + lane];
      float eacc = 0.f;
      for (int s = 0; s <= p; ++s) {
        const int m = q - s;
        eacc += r * Fb[m * 64 + lane];
        const float* Fm = Fw + (size_t)m * 4096;
        float r0 = 0.f, r1 = 0.f, r2 = 0.f, r3 = 0.f;
        for (int j = 0; j < 64; j += 4) {
          r0 += __shfl(r, j,     64) * Fm[j * 64 + lane];
          r1 += __shfl(r, j + 1, 64) * Fm[(j + 1) * 64 + lane];
          r2 += __shfl(r, j + 2, 64) * Fm[(j + 2) * 64 + lane];
          r3 += __shfl(r, j + 3, 64) * Fm[(j + 3) * 64 + lane];
        }
        r = (r0 + r1) + (r2 + r3);
      }
      eacc = sum64(eacc);
      pub_write(&up[p * 64 + lane], 1u, r);
      if (lane == 0) pub_write(&ep[p], 1u, eacc + Hb[q]);
    }
    return;
  }

  if (blk < 7) {
    // ================= V-column chains (1 wave per column) =================
    float* vb = (float*)smem + w * 64;
    const int c = (blk - 2) * 8 + w;
    if (c > 32) return;
    if (c == 32) {
      pub_write(&wp[32 * 64 + lane], 1u, spin_read(&kp[31 * 64 + lane], 32u));
      return;
    }
    const int t0 = (c == 0) ? 0 : c;
    float v = (c == 0) ? s0[lane] : spin_read(&kp[(c - 1) * 64 + lane], (unsigned)c);
    f32x4 fn[16];
    {
      const float* Fr = Fw + (size_t)t0 * 4096 + lane * 64;
      #pragma unroll
      for (int jc = 0; jc < 16; ++jc) fn[jc] = *(const f32x4*)(Fr + jc * 4);
    }
    float hn  = Hw[t0 * 64 + lane];
    float fbn = (c == 0) ? Fb[t0 * 64 + lane] : 0.f;
    for (int t = t0; t < 32; ++t) {
      vb[lane] = v;
      f32x4 fc[16];
      #pragma unroll
      for (int jc = 0; jc < 16; ++jc) fc[jc] = fn[jc];
      const float ht = hn, fbt = fbn;
      if (t + 1 < 32) {
        const float* Fr = Fw + (size_t)(t + 1) * 4096 + lane * 64;
        #pragma unroll
        for (int jc = 0; jc < 16; ++jc) fn[jc] = *(const f32x4*)(Fr + jc * 4);
        hn = Hw[(t + 1) * 64 + lane];
        if (c == 0) fbn = Fb[(t + 1) * 64 + lane];
      }
      float a0 = fbt, a1 = 0.f, a2 = 0.f, a3 = 0.f;
      #pragma unroll
      for (int jc = 0; jc < 16; ++jc) {
        const f32x4 vv = *(const f32x4*)(vb + jc * 4);
        a0 += fc[jc].x * vv.x; a1 += fc[jc].y * vv.y;
        a2 += fc[jc].z * vv.z; a3 += fc[jc].w * vv.w;
      }
      const float vp = (a0 + a1) + (a2 + a3);
      float hv = sum64(ht * vp);
      if (c == 0) hv += Hb[t];
      const float kt = spin_read(&kp[t * 64 + lane], (unsigned)(t + 1));
      v = vp - kt * hv;
    }
    pub_write(&wp[c * 64 + lane], 1u, v);
    return;
  }

  // ================= output GEMM blocks =================
  {
    float* Ul = (float*)smem;             // [16][68]
    float* Wl = (float*)(smem + 4352);    // [33][68]
    float* Zl = (float*)(smem + 13328);   // [16][34]
    float* El = (float*)(smem + 15504);   // [16]
    for (int idx = tid; idx < 1024; idx += 512)
      Ul[(idx >> 6) * 68 + (idx & 63)] = spin_read(&up[idx], 1u);
    for (int idx = tid; idx < 2112; idx += 512)
      Wl[(idx >> 6) * 68 + (idx & 63)] = spin_read(&wp[idx], 1u);
    if (tid < 16) El[tid] = spin_read(&ep[tid], 1u);
    __syncthreads();
    for (int idx = tid; idx < 528; idx += 512) {
      const int p = idx / 33, cc = idx - p * 33;
      const float* Up = Ul + p * 68;
      const float* Wc = Wl + cc * 68;
      float a0 = 0.f, a1 = 0.f, a2 = 0.f, a3 = 0.f;
      #pragma unroll 4
      for (int i = 0; i < 64; i += 4) {
        a0 += Up[i] * Wc[i];     a1 += Up[i + 1] * Wc[i + 1];
        a2 += Up[i + 2] * Wc[i + 2]; a3 += Up[i + 3] * Wc[i + 3];
      }
      float z = (a0 + a1) + (a2 + a3);
      if (cc == 0) z += El[p];
      Zl[p * 34 + cc] = z;
    }
    const int b = (blk - 7) * 512 + tid;
    f32x4 xr[8];
    const f32x4* xp = (const f32x4*)(x + (size_t)b * 32);
    #pragma unroll
    for (int u = 0; u < 8; ++u) xr[u] = xp[u];
    __syncthreads();
    float acc[16];
    #pragma unroll
    for (int p = 0; p < 16; ++p) acc[p] = Zl[p * 34];
    #pragma unroll
    for (int u = 0; u < 8; ++u) {
      #pragma unroll
      for (int e = 0; e < 4; ++e) {
        const float xval = xr[u][e];
        const int t = u * 4 + e;
        #pragma unroll
        for (int p = 0; p < 16; ++p) acc[p] += Zl[p * 34 + 1 + t] * xval;
      }
    }
    float4* op = (float4*)(out + (size_t)b * 16);
    op[0] = make_float4(acc[0], acc[1], acc[2], acc[3]);
    op[1] = make_float4(acc[4], acc[5], acc[6], acc[7]);
    op[2] = make_float4(acc[8], acc[9], acc[10], acc[11]);
    op[3] = make_float4(acc[12], acc[13], acc[14], acc[15]);
  }
}

extern "C" void kernel_launch(void* const* d_in, const int* in_sizes, int n_in,
                              void* d_out, int out_size, void* d_ws, size_t ws_size,
                              hipStream_t stream) {
  (void)in_sizes; (void)n_in; (void)out_size; (void)ws_size;
  const float* x  = (const float*)d_in[0];
  const float* Fw = (const float*)d_in[1];
  const float* Fb = (const float*)d_in[2];
  const float* Hw = (const float*)d_in[3];
  const float* Hb = (const float*)d_in[4];
  const float* s0 = (const float*)d_in[5];
  const float* P0 = (const float*)d_in[6];
  const float* Q  = (const float*)d_in[7];
  const float* R  = (const float*)d_in[8];
  float* out = (float*)d_out;
  unsigned long long* ws = (unsigned long long*)d_ws;

  hipMemsetAsync(d_ws, 0, WS_U64 * sizeof(unsigned long long), stream);
  kalman_fused<<<15, 512, 0, stream>>>(Fw, Fb, Hw, Hb, s0, P0, Q, R, x, out, ws);
}